// Round 4
// baseline (103.349 us; speedup 1.0000x reference)
//
#include <hip/hip_runtime.h>
#include <math.h>

#define DD 512
#define CAT_VOCAB 512
#define TIME_START 512
#define TIME_STEPS 1000
#define NOTE_START 1512
#define NOTE_RANGE 128
#define VEL_START 1640
#define VEL_BINS 32
#define DUR_START 1672
#define DUR_STEPS 1000
#define VOCAB 2672

#define VEL_BLOCKS 32
#define EW_BLOCKS 1336   // VOCAB*128 chunks / 256 threads

// float -> bf16 bits, round-to-nearest-even
__device__ __forceinline__ unsigned short f2bf(float f) {
    unsigned int u = __float_as_uint(f);
    u += 0x7FFFu + ((u >> 16) & 1u);
    return (unsigned short)(u >> 16);
}
__device__ __forceinline__ float bf2f(unsigned short b) {
    return __uint_as_float(((unsigned int)b) << 16);
}

// ---------------------------------------------------------------------------
// Table build: bf16 table[VOCAB][512].
// Blocks [0, VEL_BLOCKS): one block per velocity token (longest pole -> first).
//   Matvec done wave-per-row: coalesced float4 loads of w2 rows + shfl reduce.
// Blocks [VEL_BLOCKS, VEL_BLOCKS+EW_BLOCKS): one thread per 4-dim chunk.
// ---------------------------------------------------------------------------
__global__ __launch_bounds__(256) void build_table_kernel(
    const float* __restrict__ token_emb,
    const float* __restrict__ time_lin_w, const float* __restrict__ time_lin_b,
    const float* __restrict__ time_w,     const float* __restrict__ time_b,
    const float* __restrict__ vel_w1,     const float* __restrict__ vel_b1,
    const float* __restrict__ vel_w2,     const float* __restrict__ vel_b2,
    const float* __restrict__ vel_ln_g,   const float* __restrict__ vel_ln_b,
    const float* __restrict__ dur_lin_w,  const float* __restrict__ dur_lin_b,
    const float* __restrict__ dur_w,      const float* __restrict__ dur_b,
    unsigned short* __restrict__ table)
{
    __shared__ float h_lds[256];
    __shared__ float e_lds[512];
    __shared__ float red1[4], red2[4];

    if (blockIdx.x >= VEL_BLOCKS) {
        // ---- element-wise rows: cat / time / pitch / dur ----
        const int idx = (blockIdx.x - VEL_BLOCKS) * 256 + threadIdx.x;
        const int t = idx >> 7;          // vocab row (wave-uniform)
        const int c = idx & 127;         // chunk within row
        const int d = c * 4;

        float v[4];

        if (t < CAT_VOCAB) {
            const float4 e = *(const float4*)(token_emb + (size_t)t * DD + d);
            v[0] = e.x; v[1] = e.y; v[2] = e.z; v[3] = e.w;
        } else if (t < NOTE_START || t >= DUR_START) {
            const bool is_time = (t < NOTE_START);
            const int start = is_time ? TIME_START : DUR_START;
            const float tn = (float)(t - start) / 1000.0f;
            if (c < 64) {  // linear half, dims [0,256)
                const float* lw = is_time ? time_lin_w : dur_lin_w;
                const float* lb = is_time ? time_lin_b : dur_lin_b;
                const float4 w = *(const float4*)(lw + d);
                const float4 b = *(const float4*)(lb + d);
                v[0] = tn * w.x + b.x; v[1] = tn * w.y + b.y;
                v[2] = tn * w.z + b.z; v[3] = tn * w.w + b.w;
            } else {       // periodic half, dims [256,512)
                const float* pw = is_time ? time_w : dur_w;
                const float* pb = is_time ? time_b : dur_b;
                const float4 w = *(const float4*)(pw + d - 256);
                const float4 b = *(const float4*)(pb + d - 256);
                v[0] = sinf(tn * w.x + b.x); v[1] = sinf(tn * w.y + b.y);
                v[2] = sinf(tn * w.z + b.z); v[3] = sinf(tn * w.w + b.w);
            }
        } else if (t < VEL_START) {
            // pitch: group i = c
            const int p = t - NOTE_START;
            const float oct = (float)(p / 12);
            const float sem = (float)(p % 12);
            const float i = (float)c;
            const float po = oct * exp2f(-i);
            const float ps = sem * 0.52359877559829887308f * (i + 1.0f);
            v[0] = sinf(po); v[1] = cosf(po); v[2] = sinf(ps); v[3] = cosf(ps);
        } else {
            return;  // velocity rows handled by vel blocks
        }

        ushort4 pk;
        pk.x = f2bf(v[0]); pk.y = f2bf(v[1]); pk.z = f2bf(v[2]); pk.w = f2bf(v[3]);
        *(ushort4*)(table + (size_t)t * DD + d) = pk;
        return;
    }

    // ---- velocity block: one token, wave-per-row coalesced matvec ----
    const int b = blockIdx.x;                 // 0..31
    const int row = VEL_START + b;
    const float vn = (float)b / 32.0f;
    const int tid = threadIdx.x;
    const int lane = tid & 63;
    const int wave = tid >> 6;

    // h[j] = gelu(vn*w1[j]+b1[j])
    {
        const float x = vn * vel_w1[tid] + vel_b1[tid];
        h_lds[tid] = 0.5f * x * (1.0f + erff(x * 0.70710678118654752440f));
    }
    __syncthreads();

    // each lane keeps h[4*lane .. 4*lane+3] (matches its w2 columns)
    const float4 hv = *(const float4*)(h_lds + lane * 4);

    // wave handles rows [wave*128, wave*128+128)
    const int r0 = wave * 128;
    for (int r = 0; r < 128; ++r) {
        const int d = r0 + r;
        const float4 w2v = *(const float4*)(vel_w2 + (size_t)d * 256 + lane * 4);
        float p = w2v.x * hv.x + w2v.y * hv.y + w2v.z * hv.z + w2v.w * hv.w;
        #pragma unroll
        for (int off = 32; off > 0; off >>= 1) p += __shfl_xor(p, off);
        if (lane == 0) e_lds[d] = p + vel_b2[d];
    }
    __syncthreads();

    // LayerNorm over 512 values (thread covers dims tid and tid+256)
    const float e0 = e_lds[tid], e1 = e_lds[tid + 256];
    float s = e0 + e1;
    #pragma unroll
    for (int off = 32; off > 0; off >>= 1) s += __shfl_xor(s, off);
    if (lane == 0) red1[wave] = s;
    __syncthreads();
    const float mu = (red1[0] + red1[1] + red1[2] + red1[3]) * (1.0f / 512.0f);

    float sv = (e0 - mu) * (e0 - mu) + (e1 - mu) * (e1 - mu);
    #pragma unroll
    for (int off = 32; off > 0; off >>= 1) sv += __shfl_xor(sv, off);
    if (lane == 0) red2[wave] = sv;
    __syncthreads();
    const float var = (red2[0] + red2[1] + red2[2] + red2[3]) * (1.0f / 512.0f);
    const float inv = 1.0f / sqrtf(var + 1e-5f);

    const float o0 = vel_ln_g[tid] * (e0 - mu) * inv + vel_ln_b[tid];
    const float o1 = vel_ln_g[tid + 256] * (e1 - mu) * inv + vel_ln_b[tid + 256];
    table[(size_t)row * DD + tid] = f2bf(o0);
    table[(size_t)row * DD + tid + 256] = f2bf(o1);
}

// ---------------------------------------------------------------------------
// Gather: out[c] = cvt_fp32(table_bf16[tok(c)*128 + (c&127)]). Branch-free.
// ---------------------------------------------------------------------------
__global__ __launch_bounds__(256) void gather_kernel(
    const int* __restrict__ tokens,
    const ushort4* __restrict__ table,   // bf16 table, 8B per 4-dim chunk
    float4* __restrict__ out,
    int total_chunks)
{
    const int stride = gridDim.x * blockDim.x;
    int c = blockIdx.x * blockDim.x + threadIdx.x;

    for (; c + 3 * stride < total_chunks; c += 4 * stride) {
        const int c0 = c, c1 = c + stride, c2 = c + 2 * stride, c3 = c + 3 * stride;
        const int t0 = tokens[c0 >> 7];
        const int t1 = tokens[c1 >> 7];
        const int t2 = tokens[c2 >> 7];
        const int t3 = tokens[c3 >> 7];
        const ushort4 v0 = table[(size_t)t0 * 128 + (c0 & 127)];
        const ushort4 v1 = table[(size_t)t1 * 128 + (c1 & 127)];
        const ushort4 v2 = table[(size_t)t2 * 128 + (c2 & 127)];
        const ushort4 v3 = table[(size_t)t3 * 128 + (c3 & 127)];
        out[c0] = make_float4(bf2f(v0.x), bf2f(v0.y), bf2f(v0.z), bf2f(v0.w));
        out[c1] = make_float4(bf2f(v1.x), bf2f(v1.y), bf2f(v1.z), bf2f(v1.w));
        out[c2] = make_float4(bf2f(v2.x), bf2f(v2.y), bf2f(v2.z), bf2f(v2.w));
        out[c3] = make_float4(bf2f(v3.x), bf2f(v3.y), bf2f(v3.z), bf2f(v3.w));
    }
    for (; c < total_chunks; c += stride) {
        const int t = tokens[c >> 7];
        const ushort4 v = table[(size_t)t * 128 + (c & 127)];
        out[c] = make_float4(bf2f(v.x), bf2f(v.y), bf2f(v.z), bf2f(v.w));
    }
}

// ---------------------------------------------------------------------------
// Fallback (ws too small): direct per-token kernel (R1).
// ---------------------------------------------------------------------------
__global__ __launch_bounds__(256) void music_emb_fallback(
    const int* __restrict__ tokens,
    const float* __restrict__ token_emb,
    const float* __restrict__ time_lin_w, const float* __restrict__ time_lin_b,
    const float* __restrict__ time_w,     const float* __restrict__ time_b,
    const float* __restrict__ vel_w1,     const float* __restrict__ vel_b1,
    const float* __restrict__ vel_w2,     const float* __restrict__ vel_b2,
    const float* __restrict__ vel_ln_g,   const float* __restrict__ vel_ln_b,
    const float* __restrict__ dur_lin_w,  const float* __restrict__ dur_lin_b,
    const float* __restrict__ dur_w,      const float* __restrict__ dur_b,
    float* __restrict__ out, int n_tokens)
{
    const int wave = threadIdx.x >> 6;
    const int lane = threadIdx.x & 63;
    const int tok_idx = blockIdx.x * 4 + wave;
    if (tok_idx >= n_tokens) return;

    const int t = tokens[tok_idx];
    float* __restrict__ orow = out + (size_t)tok_idx * DD;
    const int d0 = lane * 4;
    const int d1 = 256 + lane * 4;
    float4 r0, r1;

    if (t < CAT_VOCAB) {
        r0 = *(const float4*)(token_emb + (size_t)t * DD + d0);
        r1 = *(const float4*)(token_emb + (size_t)t * DD + d1);
    } else if (t < NOTE_START || (t >= DUR_START && t < DUR_START + DUR_STEPS)) {
        const bool is_time = (t < NOTE_START);
        const float* lw = is_time ? time_lin_w : dur_lin_w;
        const float* lb = is_time ? time_lin_b : dur_lin_b;
        const float* pw = is_time ? time_w    : dur_w;
        const float* pb = is_time ? time_b    : dur_b;
        const int start = is_time ? TIME_START : DUR_START;
        const float tn = (float)(t - start) / 1000.0f;
        float a[4], p[4];
        #pragma unroll
        for (int k = 0; k < 4; ++k) {
            a[k] = tn * lw[d0 + k] + lb[d0 + k];
            p[k] = sinf(tn * pw[d0 + k] + pb[d0 + k]);
        }
        r0 = make_float4(a[0], a[1], a[2], a[3]);
        r1 = make_float4(p[0], p[1], p[2], p[3]);
    } else if (t < NOTE_START + NOTE_RANGE) {
        const int p = t - NOTE_START;
        const float oct = (float)(p / 12);
        const float sem = (float)(p % 12);
        const float cc = 0.52359877559829887308f;
        {
            const float i = (float)lane;
            const float po = oct * exp2f(-i);
            const float ps = (sem * cc) * (i + 1.0f);
            r0 = make_float4(sinf(po), cosf(po), sinf(ps), cosf(ps));
        }
        {
            const float i = (float)(64 + lane);
            const float po = oct * exp2f(-i);
            const float ps = (sem * cc) * (i + 1.0f);
            r1 = make_float4(sinf(po), cosf(po), sinf(ps), cosf(ps));
        }
    } else if (t < VEL_START + VEL_BINS) {
        const float vn = (float)(t - VEL_START) / 32.0f;
        float hj[4];
        #pragma unroll
        for (int k = 0; k < 4; ++k) {
            const float x = vn * vel_w1[d0 + k] + vel_b1[d0 + k];
            hj[k] = 0.5f * x * (1.0f + erff(x * 0.70710678118654752440f));
        }
        float e0[4], e1[4];
        #pragma unroll
        for (int k = 0; k < 4; ++k) { e0[k] = vel_b2[d0 + k]; e1[k] = vel_b2[d1 + k]; }
        for (int src = 0; src < 64; ++src) {
            const float h0 = __shfl(hj[0], src);
            const float h1 = __shfl(hj[1], src);
            const float h2 = __shfl(hj[2], src);
            const float h3 = __shfl(hj[3], src);
            const int j = src << 2;
            #pragma unroll
            for (int k = 0; k < 4; ++k) {
                const float4 wa = *(const float4*)(vel_w2 + (size_t)(d0 + k) * 256 + j);
                const float4 wb = *(const float4*)(vel_w2 + (size_t)(d1 + k) * 256 + j);
                e0[k] += h0 * wa.x + h1 * wa.y + h2 * wa.z + h3 * wa.w;
                e1[k] += h0 * wb.x + h1 * wb.y + h2 * wb.z + h3 * wb.w;
            }
        }
        float s1 = 0.0f;
        #pragma unroll
        for (int k = 0; k < 4; ++k) s1 += e0[k] + e1[k];
        #pragma unroll
        for (int off = 32; off > 0; off >>= 1) s1 += __shfl_xor(s1, off);
        const float mu = s1 * (1.0f / 512.0f);
        float s2 = 0.0f;
        #pragma unroll
        for (int k = 0; k < 4; ++k) {
            const float a = e0[k] - mu, bb = e1[k] - mu;
            s2 += a * a + bb * bb;
        }
        #pragma unroll
        for (int off = 32; off > 0; off >>= 1) s2 += __shfl_xor(s2, off);
        const float inv = 1.0f / sqrtf(s2 * (1.0f / 512.0f) + 1e-5f);
        #pragma unroll
        for (int k = 0; k < 4; ++k) {
            e0[k] = vel_ln_g[d0 + k] * (e0[k] - mu) * inv + vel_ln_b[d0 + k];
            e1[k] = vel_ln_g[d1 + k] * (e1[k] - mu) * inv + vel_ln_b[d1 + k];
        }
        r0 = make_float4(e0[0], e0[1], e0[2], e0[3]);
        r1 = make_float4(e1[0], e1[1], e1[2], e1[3]);
    } else {
        r0 = make_float4(0.f, 0.f, 0.f, 0.f);
        r1 = make_float4(0.f, 0.f, 0.f, 0.f);
    }

    *(float4*)(orow + d0) = r0;
    *(float4*)(orow + d1) = r1;
}

extern "C" void kernel_launch(void* const* d_in, const int* in_sizes, int n_in,
                              void* d_out, int out_size, void* d_ws, size_t ws_size,
                              hipStream_t stream) {
    const int*   tokens     = (const int*)  d_in[0];
    const float* token_emb  = (const float*)d_in[1];
    const float* time_lin_w = (const float*)d_in[2];
    const float* time_lin_b = (const float*)d_in[3];
    const float* time_w     = (const float*)d_in[4];
    const float* time_b     = (const float*)d_in[5];
    const float* vel_w1     = (const float*)d_in[6];
    const float* vel_b1     = (const float*)d_in[7];
    const float* vel_w2     = (const float*)d_in[8];
    const float* vel_b2     = (const float*)d_in[9];
    const float* vel_ln_g   = (const float*)d_in[10];
    const float* vel_ln_b   = (const float*)d_in[11];
    const float* dur_lin_w  = (const float*)d_in[12];
    const float* dur_lin_b  = (const float*)d_in[13];
    const float* dur_w      = (const float*)d_in[14];
    const float* dur_b      = (const float*)d_in[15];
    float* out = (float*)d_out;

    const int n_tokens = in_sizes[0];                                        // 65536
    const size_t table_bytes = (size_t)VOCAB * DD * sizeof(unsigned short);  // ~2.7 MB

    if (ws_size >= table_bytes) {
        unsigned short* table = (unsigned short*)d_ws;

        hipLaunchKernelGGL(build_table_kernel,
                           dim3(VEL_BLOCKS + EW_BLOCKS), dim3(256), 0, stream,
                           token_emb,
                           time_lin_w, time_lin_b, time_w, time_b,
                           vel_w1, vel_b1, vel_w2, vel_b2, vel_ln_g, vel_ln_b,
                           dur_lin_w, dur_lin_b, dur_w, dur_b,
                           table);

        const int total_chunks = n_tokens * (DD / 4);
        hipLaunchKernelGGL(gather_kernel, dim3(4096), dim3(256), 0, stream,
                           tokens, (const ushort4*)table, (float4*)out, total_chunks);
    } else {
        const int blocks = (n_tokens + 3) / 4;
        hipLaunchKernelGGL(music_emb_fallback, dim3(blocks), dim3(256), 0, stream,
                           tokens, token_emb,
                           time_lin_w, time_lin_b, time_w, time_b,
                           vel_w1, vel_b1, vel_w2, vel_b2, vel_ln_g, vel_ln_b,
                           dur_lin_w, dur_lin_b, dur_w, dur_b,
                           out, n_tokens);
    }
}

// Round 5
// 57.127 us; speedup vs baseline: 1.8091x; 1.8091x over previous
//
#include <hip/hip_runtime.h>
#include <math.h>

#define DD 512
#define CAT_VOCAB 512
#define TIME_START 512
#define TIME_STEPS 1000
#define NOTE_START 1512
#define NOTE_RANGE 128
#define VEL_START 1640
#define VEL_BINS 32
#define DUR_START 1672
#define DUR_STEPS 1000
#define VOCAB 2672

#define VEL_BLOCKS 32
#define EW_BLOCKS 1336   // VOCAB*128 chunks / 256 threads

// float -> bf16 bits, round-to-nearest-even
__device__ __forceinline__ unsigned short f2bf(float f) {
    unsigned int u = __float_as_uint(f);
    u += 0x7FFFu + ((u >> 16) & 1u);
    return (unsigned short)(u >> 16);
}
__device__ __forceinline__ float bf2f(unsigned short b) {
    return __uint_as_float(((unsigned int)b) << 16);
}
__device__ __forceinline__ float gelu_exact(float x) {
    return 0.5f * x * (1.0f + erff(x * 0.70710678118654752440f));
}

// ---------------------------------------------------------------------------
// Table build: bf16 table[VOCAB][512].
// Blocks [0, VEL_BLOCKS): one block per velocity token.
//   Coalesced wave-per-row matvec, 8 rows in flight (independent shfl trees).
// Blocks [VEL_BLOCKS, ...): one thread per 4-dim chunk (cat/time/pitch/dur).
// ---------------------------------------------------------------------------
__global__ __launch_bounds__(256) void build_table_kernel(
    const float* __restrict__ token_emb,
    const float* __restrict__ time_lin_w, const float* __restrict__ time_lin_b,
    const float* __restrict__ time_w,     const float* __restrict__ time_b,
    const float* __restrict__ vel_w1,     const float* __restrict__ vel_b1,
    const float* __restrict__ vel_w2,     const float* __restrict__ vel_b2,
    const float* __restrict__ vel_ln_g,   const float* __restrict__ vel_ln_b,
    const float* __restrict__ dur_lin_w,  const float* __restrict__ dur_lin_b,
    const float* __restrict__ dur_w,      const float* __restrict__ dur_b,
    unsigned short* __restrict__ table)
{
    __shared__ float e_lds[512];
    __shared__ float red1[4], red2[4];

    if (blockIdx.x >= VEL_BLOCKS) {
        // ---- element-wise rows: cat / time / pitch / dur ----
        const int idx = (blockIdx.x - VEL_BLOCKS) * 256 + threadIdx.x;
        const int t = idx >> 7;          // vocab row (wave-uniform)
        const int c = idx & 127;         // chunk within row
        const int d = c * 4;

        float v[4];

        if (t < CAT_VOCAB) {
            const float4 e = *(const float4*)(token_emb + (size_t)t * DD + d);
            v[0] = e.x; v[1] = e.y; v[2] = e.z; v[3] = e.w;
        } else if (t < NOTE_START || t >= DUR_START) {
            const bool is_time = (t < NOTE_START);
            const int start = is_time ? TIME_START : DUR_START;
            const float tn = (float)(t - start) / 1000.0f;
            if (c < 64) {  // linear half, dims [0,256)
                const float* lw = is_time ? time_lin_w : dur_lin_w;
                const float* lb = is_time ? time_lin_b : dur_lin_b;
                const float4 w = *(const float4*)(lw + d);
                const float4 b = *(const float4*)(lb + d);
                v[0] = tn * w.x + b.x; v[1] = tn * w.y + b.y;
                v[2] = tn * w.z + b.z; v[3] = tn * w.w + b.w;
            } else {       // periodic half, dims [256,512)
                const float* pw = is_time ? time_w : dur_w;
                const float* pb = is_time ? time_b : dur_b;
                const float4 w = *(const float4*)(pw + d - 256);
                const float4 b = *(const float4*)(pb + d - 256);
                v[0] = sinf(tn * w.x + b.x); v[1] = sinf(tn * w.y + b.y);
                v[2] = sinf(tn * w.z + b.z); v[3] = sinf(tn * w.w + b.w);
            }
        } else if (t < VEL_START) {
            // pitch: group i = c
            const int p = t - NOTE_START;
            const float oct = (float)(p / 12);
            const float sem = (float)(p % 12);
            const float i = (float)c;
            const float po = oct * exp2f(-i);
            const float ps = sem * 0.52359877559829887308f * (i + 1.0f);
            v[0] = sinf(po); v[1] = cosf(po); v[2] = sinf(ps); v[3] = cosf(ps);
        } else {
            return;  // velocity rows handled by vel blocks
        }

        ushort4 pk;
        pk.x = f2bf(v[0]); pk.y = f2bf(v[1]); pk.z = f2bf(v[2]); pk.w = f2bf(v[3]);
        *(ushort4*)(table + (size_t)t * DD + d) = pk;
        return;
    }

    // ---- velocity block: one token ----
    const int b = blockIdx.x;                 // 0..31
    const int row = VEL_START + b;
    const float vn = (float)b / 32.0f;
    const int tid = threadIdx.x;
    const int lane = tid & 63;
    const int wave = tid >> 6;

    // lane-local h[4*lane .. 4*lane+3] in registers (coalesced w1/b1 loads)
    const float4 w1v = *(const float4*)(vel_w1 + lane * 4);
    const float4 b1v = *(const float4*)(vel_b1 + lane * 4);
    float4 hv;
    hv.x = gelu_exact(vn * w1v.x + b1v.x);
    hv.y = gelu_exact(vn * w1v.y + b1v.y);
    hv.z = gelu_exact(vn * w1v.z + b1v.z);
    hv.w = gelu_exact(vn * w1v.w + b1v.w);

    // wave handles rows [wave*128, wave*128+128), 8 rows in flight
    const int r0 = wave * 128;
    for (int rg = 0; rg < 128; rg += 8) {
        float p[8];
        #pragma unroll
        for (int k = 0; k < 8; ++k) {
            const int d = r0 + rg + k;
            const float4 w2v = *(const float4*)(vel_w2 + (size_t)d * 256 + lane * 4);
            p[k] = w2v.x * hv.x + w2v.y * hv.y + w2v.z * hv.z + w2v.w * hv.w;
        }
        // 8 independent 6-level butterfly reductions, interleaved
        #pragma unroll
        for (int off = 32; off > 0; off >>= 1) {
            #pragma unroll
            for (int k = 0; k < 8; ++k) p[k] += __shfl_xor(p[k], off);
        }
        // static-index predicated writes (avoid runtime-indexed array)
        #pragma unroll
        for (int k = 0; k < 8; ++k) {
            if (lane == k) e_lds[r0 + rg + k] = p[k] + vel_b2[r0 + rg + k];
        }
    }
    __syncthreads();

    // LayerNorm over 512 values (thread covers dims tid and tid+256)
    const float e0 = e_lds[tid], e1 = e_lds[tid + 256];
    float s = e0 + e1;
    #pragma unroll
    for (int off = 32; off > 0; off >>= 1) s += __shfl_xor(s, off);
    if (lane == 0) red1[wave] = s;
    __syncthreads();
    const float mu = (red1[0] + red1[1] + red1[2] + red1[3]) * (1.0f / 512.0f);

    float sv = (e0 - mu) * (e0 - mu) + (e1 - mu) * (e1 - mu);
    #pragma unroll
    for (int off = 32; off > 0; off >>= 1) sv += __shfl_xor(sv, off);
    if (lane == 0) red2[wave] = sv;
    __syncthreads();
    const float var = (red2[0] + red2[1] + red2[2] + red2[3]) * (1.0f / 512.0f);
    const float inv = 1.0f / sqrtf(var + 1e-5f);

    const float o0 = vel_ln_g[tid] * (e0 - mu) * inv + vel_ln_b[tid];
    const float o1 = vel_ln_g[tid + 256] * (e1 - mu) * inv + vel_ln_b[tid + 256];
    table[(size_t)row * DD + tid] = f2bf(o0);
    table[(size_t)row * DD + tid + 256] = f2bf(o1);
}

// ---------------------------------------------------------------------------
// Gather: out[c] = cvt_fp32(table_bf16[tok(c)*128 + (c&127)]). Branch-free.
// ---------------------------------------------------------------------------
__global__ __launch_bounds__(256) void gather_kernel(
    const int* __restrict__ tokens,
    const ushort4* __restrict__ table,   // bf16 table, 8B per 4-dim chunk
    float4* __restrict__ out,
    int total_chunks)
{
    const int stride = gridDim.x * blockDim.x;
    int c = blockIdx.x * blockDim.x + threadIdx.x;

    for (; c + 3 * stride < total_chunks; c += 4 * stride) {
        const int c0 = c, c1 = c + stride, c2 = c + 2 * stride, c3 = c + 3 * stride;
        const int t0 = tokens[c0 >> 7];
        const int t1 = tokens[c1 >> 7];
        const int t2 = tokens[c2 >> 7];
        const int t3 = tokens[c3 >> 7];
        const ushort4 v0 = table[(size_t)t0 * 128 + (c0 & 127)];
        const ushort4 v1 = table[(size_t)t1 * 128 + (c1 & 127)];
        const ushort4 v2 = table[(size_t)t2 * 128 + (c2 & 127)];
        const ushort4 v3 = table[(size_t)t3 * 128 + (c3 & 127)];
        out[c0] = make_float4(bf2f(v0.x), bf2f(v0.y), bf2f(v0.z), bf2f(v0.w));
        out[c1] = make_float4(bf2f(v1.x), bf2f(v1.y), bf2f(v1.z), bf2f(v1.w));
        out[c2] = make_float4(bf2f(v2.x), bf2f(v2.y), bf2f(v2.z), bf2f(v2.w));
        out[c3] = make_float4(bf2f(v3.x), bf2f(v3.y), bf2f(v3.z), bf2f(v3.w));
    }
    for (; c < total_chunks; c += stride) {
        const int t = tokens[c >> 7];
        const ushort4 v = table[(size_t)t * 128 + (c & 127)];
        out[c] = make_float4(bf2f(v.x), bf2f(v.y), bf2f(v.z), bf2f(v.w));
    }
}

// ---------------------------------------------------------------------------
// Fallback (ws too small): direct per-token kernel (R1).
// ---------------------------------------------------------------------------
__global__ __launch_bounds__(256) void music_emb_fallback(
    const int* __restrict__ tokens,
    const float* __restrict__ token_emb,
    const float* __restrict__ time_lin_w, const float* __restrict__ time_lin_b,
    const float* __restrict__ time_w,     const float* __restrict__ time_b,
    const float* __restrict__ vel_w1,     const float* __restrict__ vel_b1,
    const float* __restrict__ vel_w2,     const float* __restrict__ vel_b2,
    const float* __restrict__ vel_ln_g,   const float* __restrict__ vel_ln_b,
    const float* __restrict__ dur_lin_w,  const float* __restrict__ dur_lin_b,
    const float* __restrict__ dur_w,      const float* __restrict__ dur_b,
    float* __restrict__ out, int n_tokens)
{
    const int wave = threadIdx.x >> 6;
    const int lane = threadIdx.x & 63;
    const int tok_idx = blockIdx.x * 4 + wave;
    if (tok_idx >= n_tokens) return;

    const int t = tokens[tok_idx];
    float* __restrict__ orow = out + (size_t)tok_idx * DD;
    const int d0 = lane * 4;
    const int d1 = 256 + lane * 4;
    float4 r0, r1;

    if (t < CAT_VOCAB) {
        r0 = *(const float4*)(token_emb + (size_t)t * DD + d0);
        r1 = *(const float4*)(token_emb + (size_t)t * DD + d1);
    } else if (t < NOTE_START || (t >= DUR_START && t < DUR_START + DUR_STEPS)) {
        const bool is_time = (t < NOTE_START);
        const float* lw = is_time ? time_lin_w : dur_lin_w;
        const float* lb = is_time ? time_lin_b : dur_lin_b;
        const float* pw = is_time ? time_w    : dur_w;
        const float* pb = is_time ? time_b    : dur_b;
        const int start = is_time ? TIME_START : DUR_START;
        const float tn = (float)(t - start) / 1000.0f;
        float a[4], p[4];
        #pragma unroll
        for (int k = 0; k < 4; ++k) {
            a[k] = tn * lw[d0 + k] + lb[d0 + k];
            p[k] = sinf(tn * pw[d0 + k] + pb[d0 + k]);
        }
        r0 = make_float4(a[0], a[1], a[2], a[3]);
        r1 = make_float4(p[0], p[1], p[2], p[3]);
    } else if (t < NOTE_START + NOTE_RANGE) {
        const int p = t - NOTE_START;
        const float oct = (float)(p / 12);
        const float sem = (float)(p % 12);
        const float cc = 0.52359877559829887308f;
        {
            const float i = (float)lane;
            const float po = oct * exp2f(-i);
            const float ps = (sem * cc) * (i + 1.0f);
            r0 = make_float4(sinf(po), cosf(po), sinf(ps), cosf(ps));
        }
        {
            const float i = (float)(64 + lane);
            const float po = oct * exp2f(-i);
            const float ps = (sem * cc) * (i + 1.0f);
            r1 = make_float4(sinf(po), cosf(po), sinf(ps), cosf(ps));
        }
    } else if (t < VEL_START + VEL_BINS) {
        const float vn = (float)(t - VEL_START) / 32.0f;
        float hj[4];
        #pragma unroll
        for (int k = 0; k < 4; ++k) {
            const float x = vn * vel_w1[d0 + k] + vel_b1[d0 + k];
            hj[k] = gelu_exact(x);
        }
        float e0[4], e1[4];
        #pragma unroll
        for (int k = 0; k < 4; ++k) { e0[k] = vel_b2[d0 + k]; e1[k] = vel_b2[d1 + k]; }
        for (int src = 0; src < 64; ++src) {
            const float h0 = __shfl(hj[0], src);
            const float h1 = __shfl(hj[1], src);
            const float h2 = __shfl(hj[2], src);
            const float h3 = __shfl(hj[3], src);
            const int j = src << 2;
            #pragma unroll
            for (int k = 0; k < 4; ++k) {
                const float4 wa = *(const float4*)(vel_w2 + (size_t)(d0 + k) * 256 + j);
                const float4 wb = *(const float4*)(vel_w2 + (size_t)(d1 + k) * 256 + j);
                e0[k] += h0 * wa.x + h1 * wa.y + h2 * wa.z + h3 * wa.w;
                e1[k] += h0 * wb.x + h1 * wb.y + h2 * wb.z + h3 * wb.w;
            }
        }
        float s1 = 0.0f;
        #pragma unroll
        for (int k = 0; k < 4; ++k) s1 += e0[k] + e1[k];
        #pragma unroll
        for (int off = 32; off > 0; off >>= 1) s1 += __shfl_xor(s1, off);
        const float mu = s1 * (1.0f / 512.0f);
        float s2 = 0.0f;
        #pragma unroll
        for (int k = 0; k < 4; ++k) {
            const float a = e0[k] - mu, bb = e1[k] - mu;
            s2 += a * a + bb * bb;
        }
        #pragma unroll
        for (int off = 32; off > 0; off >>= 1) s2 += __shfl_xor(s2, off);
        const float inv = 1.0f / sqrtf(s2 * (1.0f / 512.0f) + 1e-5f);
        #pragma unroll
        for (int k = 0; k < 4; ++k) {
            e0[k] = vel_ln_g[d0 + k] * (e0[k] - mu) * inv + vel_ln_b[d0 + k];
            e1[k] = vel_ln_g[d1 + k] * (e1[k] - mu) * inv + vel_ln_b[d1 + k];
        }
        r0 = make_float4(e0[0], e0[1], e0[2], e0[3]);
        r1 = make_float4(e1[0], e1[1], e1[2], e1[3]);
    } else {
        r0 = make_float4(0.f, 0.f, 0.f, 0.f);
        r1 = make_float4(0.f, 0.f, 0.f, 0.f);
    }

    *(float4*)(orow + d0) = r0;
    *(float4*)(orow + d1) = r1;
}

extern "C" void kernel_launch(void* const* d_in, const int* in_sizes, int n_in,
                              void* d_out, int out_size, void* d_ws, size_t ws_size,
                              hipStream_t stream) {
    const int*   tokens     = (const int*)  d_in[0];
    const float* token_emb  = (const float*)d_in[1];
    const float* time_lin_w = (const float*)d_in[2];
    const float* time_lin_b = (const float*)d_in[3];
    const float* time_w     = (const float*)d_in[4];
    const float* time_b     = (const float*)d_in[5];
    const float* vel_w1     = (const float*)d_in[6];
    const float* vel_b1     = (const float*)d_in[7];
    const float* vel_w2     = (const float*)d_in[8];
    const float* vel_b2     = (const float*)d_in[9];
    const float* vel_ln_g   = (const float*)d_in[10];
    const float* vel_ln_b   = (const float*)d_in[11];
    const float* dur_lin_w  = (const float*)d_in[12];
    const float* dur_lin_b  = (const float*)d_in[13];
    const float* dur_w      = (const float*)d_in[14];
    const float* dur_b      = (const float*)d_in[15];
    float* out = (float*)d_out;

    const int n_tokens = in_sizes[0];                                        // 65536
    const size_t table_bytes = (size_t)VOCAB * DD * sizeof(unsigned short);  // ~2.7 MB

    if (ws_size >= table_bytes) {
        unsigned short* table = (unsigned short*)d_ws;

        hipLaunchKernelGGL(build_table_kernel,
                           dim3(VEL_BLOCKS + EW_BLOCKS), dim3(256), 0, stream,
                           token_emb,
                           time_lin_w, time_lin_b, time_w, time_b,
                           vel_w1, vel_b1, vel_w2, vel_b2, vel_ln_g, vel_ln_b,
                           dur_lin_w, dur_lin_b, dur_w, dur_b,
                           table);

        const int total_chunks = n_tokens * (DD / 4);
        hipLaunchKernelGGL(gather_kernel, dim3(4096), dim3(256), 0, stream,
                           tokens, (const ushort4*)table, (float4*)out, total_chunks);
    } else {
        const int blocks = (n_tokens + 3) / 4;
        hipLaunchKernelGGL(music_emb_fallback, dim3(blocks), dim3(256), 0, stream,
                           tokens, token_emb,
                           time_lin_w, time_lin_b, time_w, time_b,
                           vel_w1, vel_b1, vel_w2, vel_b2, vel_ln_g, vel_ln_b,
                           dur_lin_w, dur_lin_b, dur_w, dur_b,
                           out, n_tokens);
    }
}

// Round 6
// 48.687 us; speedup vs baseline: 2.1227x; 1.1734x over previous
//
#include <hip/hip_runtime.h>
#include <math.h>

#define DD 512
#define CAT_VOCAB 512
#define TIME_START 512
#define TIME_STEPS 1000
#define NOTE_START 1512
#define NOTE_RANGE 128
#define VEL_START 1640
#define VEL_BINS 32
#define DUR_START 1672
#define DUR_STEPS 1000
#define VOCAB 2672

typedef float f32x4 __attribute__((ext_vector_type(4)));

__device__ __forceinline__ float gelu_exact(float x) {
    return 0.5f * x * (1.0f + erff(x * 0.70710678118654752440f));
}

// hardware trig: reduce to revolutions in [0,1), then v_sin/v_cos.
// |x| <= ~740 rad here -> reduction error <= ~5e-5, far under threshold.
__device__ __forceinline__ float fsin(float x) {
    float r = x * 0.15915494309189535f;   // x / (2*pi)
    r = r - floorf(r);
    return __builtin_amdgcn_sinf(r);
}
__device__ __forceinline__ float fcos(float x) {
    float r = x * 0.15915494309189535f;
    r = r - floorf(r);
    return __builtin_amdgcn_cosf(r);
}

// ---------------------------------------------------------------------------
// Pre-kernel: fp32 velocity table [32][512] into d_ws. One block per vel bin.
// Coalesced wave-per-row matvec, 8 rows in flight (independent shfl trees).
// ---------------------------------------------------------------------------
__global__ __launch_bounds__(256) void vel_table_kernel(
    const float* __restrict__ vel_w1, const float* __restrict__ vel_b1,
    const float* __restrict__ vel_w2, const float* __restrict__ vel_b2,
    const float* __restrict__ vel_ln_g, const float* __restrict__ vel_ln_b,
    float* __restrict__ veltab)
{
    __shared__ float e_lds[512];
    __shared__ float red1[4], red2[4];

    const int b = blockIdx.x;                 // 0..31
    const float vn = (float)b / 32.0f;
    const int tid = threadIdx.x;
    const int lane = tid & 63;
    const int wave = tid >> 6;

    // lane-local h[4*lane .. 4*lane+3] in registers (coalesced w1/b1 loads)
    const float4 w1v = *(const float4*)(vel_w1 + lane * 4);
    const float4 b1v = *(const float4*)(vel_b1 + lane * 4);
    float4 hv;
    hv.x = gelu_exact(vn * w1v.x + b1v.x);
    hv.y = gelu_exact(vn * w1v.y + b1v.y);
    hv.z = gelu_exact(vn * w1v.z + b1v.z);
    hv.w = gelu_exact(vn * w1v.w + b1v.w);

    // wave handles rows [wave*128, wave*128+128), 8 rows in flight
    const int r0 = wave * 128;
    for (int rg = 0; rg < 128; rg += 8) {
        float p[8];
        #pragma unroll
        for (int k = 0; k < 8; ++k) {
            const int d = r0 + rg + k;
            const float4 w2v = *(const float4*)(vel_w2 + (size_t)d * 256 + lane * 4);
            p[k] = w2v.x * hv.x + w2v.y * hv.y + w2v.z * hv.z + w2v.w * hv.w;
        }
        #pragma unroll
        for (int off = 32; off > 0; off >>= 1) {
            #pragma unroll
            for (int k = 0; k < 8; ++k) p[k] += __shfl_xor(p[k], off);
        }
        #pragma unroll
        for (int k = 0; k < 8; ++k) {
            if (lane == k) e_lds[r0 + rg + k] = p[k] + vel_b2[r0 + rg + k];
        }
    }
    __syncthreads();

    // LayerNorm over 512 values (thread covers dims tid and tid+256)
    const float e0 = e_lds[tid], e1 = e_lds[tid + 256];
    float s = e0 + e1;
    #pragma unroll
    for (int off = 32; off > 0; off >>= 1) s += __shfl_xor(s, off);
    if (lane == 0) red1[wave] = s;
    __syncthreads();
    const float mu = (red1[0] + red1[1] + red1[2] + red1[3]) * (1.0f / 512.0f);

    float sv = (e0 - mu) * (e0 - mu) + (e1 - mu) * (e1 - mu);
    #pragma unroll
    for (int off = 32; off > 0; off >>= 1) sv += __shfl_xor(sv, off);
    if (lane == 0) red2[wave] = sv;
    __syncthreads();
    const float var = (red2[0] + red2[1] + red2[2] + red2[3]) * (1.0f / 512.0f);
    const float inv = 1.0f / sqrtf(var + 1e-5f);

    veltab[(size_t)b * DD + tid]       = vel_ln_g[tid] * (e0 - mu) * inv + vel_ln_b[tid];
    veltab[(size_t)b * DD + tid + 256] = vel_ln_g[tid + 256] * (e1 - mu) * inv + vel_ln_b[tid + 256];
}

// ---------------------------------------------------------------------------
// Main: direct per-chunk compute. Thread handles one float4 chunk per iter.
// Token is wave-uniform (changes every 128 threads). Nontemporal stores.
// ---------------------------------------------------------------------------
__global__ __launch_bounds__(256) void direct_kernel(
    const int* __restrict__ tokens,
    const float* __restrict__ token_emb,
    const float* __restrict__ time_lin_w, const float* __restrict__ time_lin_b,
    const float* __restrict__ time_w,     const float* __restrict__ time_b,
    const float* __restrict__ dur_lin_w,  const float* __restrict__ dur_lin_b,
    const float* __restrict__ dur_w,      const float* __restrict__ dur_b,
    const float* __restrict__ veltab,
    float* __restrict__ out, int total_chunks)
{
    const int stride = gridDim.x * blockDim.x;
    for (int c = blockIdx.x * blockDim.x + threadIdx.x; c < total_chunks; c += stride) {
        const int tok = c >> 7;        // token index
        const int ch  = c & 127;       // chunk within row
        const int d   = ch * 4;        // first dim of chunk
        const int t   = tokens[tok];   // wave-uniform

        f32x4 v;

        if (t < CAT_VOCAB) {
            v = *(const f32x4*)(token_emb + (size_t)t * DD + d);
        } else if (t < NOTE_START || t >= DUR_START) {
            const bool is_time = (t < NOTE_START);
            const int start = is_time ? TIME_START : DUR_START;
            const float tn = (float)(t - start) / 1000.0f;
            if (ch < 64) {   // linear half, dims [0,256)
                const float* lw = is_time ? time_lin_w : dur_lin_w;
                const float* lb = is_time ? time_lin_b : dur_lin_b;
                const float4 w = *(const float4*)(lw + d);
                const float4 b = *(const float4*)(lb + d);
                v.x = tn * w.x + b.x; v.y = tn * w.y + b.y;
                v.z = tn * w.z + b.z; v.w = tn * w.w + b.w;
            } else {         // periodic half, dims [256,512)
                const float* pw = is_time ? time_w : dur_w;
                const float* pb = is_time ? time_b : dur_b;
                const float4 w = *(const float4*)(pw + d - 256);
                const float4 b = *(const float4*)(pb + d - 256);
                v.x = fsin(tn * w.x + b.x); v.y = fsin(tn * w.y + b.y);
                v.z = fsin(tn * w.z + b.z); v.w = fsin(tn * w.w + b.w);
            }
        } else if (t < VEL_START) {
            // pitch: group i = ch, dims (sin po, cos po, sin ps, cos ps)
            const int p = t - NOTE_START;
            const float oct = (float)(p / 12);
            const float sem = (float)(p % 12);
            const float po = oct * __builtin_amdgcn_exp2f(-(float)ch);
            const float ps = sem * 0.52359877559829887308f * ((float)ch + 1.0f);
            v.x = fsin(po); v.y = fcos(po); v.z = fsin(ps); v.w = fcos(ps);
        } else {
            // velocity: read precomputed fp32 table row (L2-resident)
            v = *(const f32x4*)(veltab + (size_t)(t - VEL_START) * DD + d);
        }

        __builtin_nontemporal_store(v, (f32x4*)(out + (size_t)c * 4));
    }
}

// ---------------------------------------------------------------------------
// Fallback (ws too small): direct per-token kernel (R1).
// ---------------------------------------------------------------------------
__global__ __launch_bounds__(256) void music_emb_fallback(
    const int* __restrict__ tokens,
    const float* __restrict__ token_emb,
    const float* __restrict__ time_lin_w, const float* __restrict__ time_lin_b,
    const float* __restrict__ time_w,     const float* __restrict__ time_b,
    const float* __restrict__ vel_w1,     const float* __restrict__ vel_b1,
    const float* __restrict__ vel_w2,     const float* __restrict__ vel_b2,
    const float* __restrict__ vel_ln_g,   const float* __restrict__ vel_ln_b,
    const float* __restrict__ dur_lin_w,  const float* __restrict__ dur_lin_b,
    const float* __restrict__ dur_w,      const float* __restrict__ dur_b,
    float* __restrict__ out, int n_tokens)
{
    const int wave = threadIdx.x >> 6;
    const int lane = threadIdx.x & 63;
    const int tok_idx = blockIdx.x * 4 + wave;
    if (tok_idx >= n_tokens) return;

    const int t = tokens[tok_idx];
    float* __restrict__ orow = out + (size_t)tok_idx * DD;
    const int d0 = lane * 4;
    const int d1 = 256 + lane * 4;
    float4 r0, r1;

    if (t < CAT_VOCAB) {
        r0 = *(const float4*)(token_emb + (size_t)t * DD + d0);
        r1 = *(const float4*)(token_emb + (size_t)t * DD + d1);
    } else if (t < NOTE_START || (t >= DUR_START && t < DUR_START + DUR_STEPS)) {
        const bool is_time = (t < NOTE_START);
        const float* lw = is_time ? time_lin_w : dur_lin_w;
        const float* lb = is_time ? time_lin_b : dur_lin_b;
        const float* pw = is_time ? time_w    : dur_w;
        const float* pb = is_time ? time_b    : dur_b;
        const int start = is_time ? TIME_START : DUR_START;
        const float tn = (float)(t - start) / 1000.0f;
        float a[4], p[4];
        #pragma unroll
        for (int k = 0; k < 4; ++k) {
            a[k] = tn * lw[d0 + k] + lb[d0 + k];
            p[k] = sinf(tn * pw[d0 + k] + pb[d0 + k]);
        }
        r0 = make_float4(a[0], a[1], a[2], a[3]);
        r1 = make_float4(p[0], p[1], p[2], p[3]);
    } else if (t < NOTE_START + NOTE_RANGE) {
        const int p = t - NOTE_START;
        const float oct = (float)(p / 12);
        const float sem = (float)(p % 12);
        const float cc = 0.52359877559829887308f;
        {
            const float i = (float)lane;
            const float po = oct * exp2f(-i);
            const float ps = (sem * cc) * (i + 1.0f);
            r0 = make_float4(sinf(po), cosf(po), sinf(ps), cosf(ps));
        }
        {
            const float i = (float)(64 + lane);
            const float po = oct * exp2f(-i);
            const float ps = (sem * cc) * (i + 1.0f);
            r1 = make_float4(sinf(po), cosf(po), sinf(ps), cosf(ps));
        }
    } else if (t < VEL_START + VEL_BINS) {
        const float vn = (float)(t - VEL_START) / 32.0f;
        float hj[4];
        #pragma unroll
        for (int k = 0; k < 4; ++k) {
            const float x = vn * vel_w1[d0 + k] + vel_b1[d0 + k];
            hj[k] = gelu_exact(x);
        }
        float e0[4], e1[4];
        #pragma unroll
        for (int k = 0; k < 4; ++k) { e0[k] = vel_b2[d0 + k]; e1[k] = vel_b2[d1 + k]; }
        for (int src = 0; src < 64; ++src) {
            const float h0 = __shfl(hj[0], src);
            const float h1 = __shfl(hj[1], src);
            const float h2 = __shfl(hj[2], src);
            const float h3 = __shfl(hj[3], src);
            const int j = src << 2;
            #pragma unroll
            for (int k = 0; k < 4; ++k) {
                const float4 wa = *(const float4*)(vel_w2 + (size_t)(d0 + k) * 256 + j);
                const float4 wb = *(const float4*)(vel_w2 + (size_t)(d1 + k) * 256 + j);
                e0[k] += h0 * wa.x + h1 * wa.y + h2 * wa.z + h3 * wa.w;
                e1[k] += h0 * wb.x + h1 * wb.y + h2 * wb.z + h3 * wb.w;
            }
        }
        float s1 = 0.0f;
        #pragma unroll
        for (int k = 0; k < 4; ++k) s1 += e0[k] + e1[k];
        #pragma unroll
        for (int off = 32; off > 0; off >>= 1) s1 += __shfl_xor(s1, off);
        const float mu = s1 * (1.0f / 512.0f);
        float s2 = 0.0f;
        #pragma unroll
        for (int k = 0; k < 4; ++k) {
            const float a = e0[k] - mu, bb = e1[k] - mu;
            s2 += a * a + bb * bb;
        }
        #pragma unroll
        for (int off = 32; off > 0; off >>= 1) s2 += __shfl_xor(s2, off);
        const float inv = 1.0f / sqrtf(s2 * (1.0f / 512.0f) + 1e-5f);
        #pragma unroll
        for (int k = 0; k < 4; ++k) {
            e0[k] = vel_ln_g[d0 + k] * (e0[k] - mu) * inv + vel_ln_b[d0 + k];
            e1[k] = vel_ln_g[d1 + k] * (e1[k] - mu) * inv + vel_ln_b[d1 + k];
        }
        r0 = make_float4(e0[0], e0[1], e0[2], e0[3]);
        r1 = make_float4(e1[0], e1[1], e1[2], e1[3]);
    } else {
        r0 = make_float4(0.f, 0.f, 0.f, 0.f);
        r1 = make_float4(0.f, 0.f, 0.f, 0.f);
    }

    *(float4*)(orow + d0) = r0;
    *(float4*)(orow + d1) = r1;
}

extern "C" void kernel_launch(void* const* d_in, const int* in_sizes, int n_in,
                              void* d_out, int out_size, void* d_ws, size_t ws_size,
                              hipStream_t stream) {
    const int*   tokens     = (const int*)  d_in[0];
    const float* token_emb  = (const float*)d_in[1];
    const float* time_lin_w = (const float*)d_in[2];
    const float* time_lin_b = (const float*)d_in[3];
    const float* time_w     = (const float*)d_in[4];
    const float* time_b     = (const float*)d_in[5];
    const float* vel_w1     = (const float*)d_in[6];
    const float* vel_b1     = (const float*)d_in[7];
    const float* vel_w2     = (const float*)d_in[8];
    const float* vel_b2     = (const float*)d_in[9];
    const float* vel_ln_g   = (const float*)d_in[10];
    const float* vel_ln_b   = (const float*)d_in[11];
    const float* dur_lin_w  = (const float*)d_in[12];
    const float* dur_lin_b  = (const float*)d_in[13];
    const float* dur_w      = (const float*)d_in[14];
    const float* dur_b      = (const float*)d_in[15];
    float* out = (float*)d_out;

    const int n_tokens = in_sizes[0];                              // 65536
    const size_t veltab_bytes = (size_t)VEL_BINS * DD * sizeof(float);  // 64 KB

    if (ws_size >= veltab_bytes) {
        float* veltab = (float*)d_ws;

        hipLaunchKernelGGL(vel_table_kernel, dim3(VEL_BINS), dim3(256), 0, stream,
                           vel_w1, vel_b1, vel_w2, vel_b2, vel_ln_g, vel_ln_b,
                           veltab);

        const int total_chunks = n_tokens * (DD / 4);              // 8.39 M
        hipLaunchKernelGGL(direct_kernel, dim3(4096), dim3(256), 0, stream,
                           tokens, token_emb,
                           time_lin_w, time_lin_b, time_w, time_b,
                           dur_lin_w, dur_lin_b, dur_w, dur_b,
                           veltab, out, total_chunks);
    } else {
        const int blocks = (n_tokens + 3) / 4;
        hipLaunchKernelGGL(music_emb_fallback, dim3(blocks), dim3(256), 0, stream,
                           tokens, token_emb,
                           time_lin_w, time_lin_b, time_w, time_b,
                           vel_w1, vel_b1, vel_w2, vel_b2, vel_ln_g, vel_ln_b,
                           dur_lin_w, dur_lin_b, dur_w, dur_b,
                           out, n_tokens);
    }
}

// Round 7
// 31.123 us; speedup vs baseline: 3.3207x; 1.5643x over previous
//
#include <hip/hip_runtime.h>
#include <math.h>

#define DD 512
#define CAT_VOCAB 512
#define TIME_START 512
#define TIME_STEPS 1000
#define NOTE_START 1512
#define NOTE_RANGE 128
#define VEL_START 1640
#define VEL_BINS 32
#define DUR_START 1672
#define DUR_STEPS 1000
#define VOCAB 2672

typedef float f32x4 __attribute__((ext_vector_type(4)));

__device__ __forceinline__ float gelu_exact(float x) {
    return 0.5f * x * (1.0f + erff(x * 0.70710678118654752440f));
}

// hardware trig: reduce to revolutions in [0,1), then v_sin/v_cos.
// |x| <= ~740 rad here -> reduction error <= ~5e-5, far under 8.25e-2 threshold.
__device__ __forceinline__ float fsin(float x) {
    float r = x * 0.15915494309189535f;   // x / (2*pi)
    r = r - floorf(r);
    return __builtin_amdgcn_sinf(r);
}
__device__ __forceinline__ float fcos(float x) {
    float r = x * 0.15915494309189535f;
    r = r - floorf(r);
    return __builtin_amdgcn_cosf(r);
}

// ---------------------------------------------------------------------------
// Kernel A: velocity e-matvec, 256 blocks = (bin b, octant o of 64 rows).
// Writes raw e[32][512] and per-octant partial stats (sum, sumsq) -> no LN here.
// Race-free (each block owns its slots), deterministic.
// ---------------------------------------------------------------------------
__global__ __launch_bounds__(256) void vel_e_kernel(
    const float* __restrict__ vel_w1, const float* __restrict__ vel_b1,
    const float* __restrict__ vel_w2, const float* __restrict__ vel_b2,
    float* __restrict__ e_tab,        // [32][512]
    float* __restrict__ stats)        // [32][8][2]
{
    __shared__ float e_lds[64];

    const int blk = blockIdx.x;           // 0..255
    const int b   = blk >> 3;             // bin 0..31
    const int o   = blk & 7;              // octant 0..7
    const float vn = (float)b / 32.0f;
    const int tid = threadIdx.x;
    const int lane = tid & 63;
    const int wave = tid >> 6;

    // lane-local h[4*lane .. 4*lane+3] in registers (coalesced w1/b1 loads)
    const float4 w1v = *(const float4*)(vel_w1 + lane * 4);
    const float4 b1v = *(const float4*)(vel_b1 + lane * 4);
    float4 hv;
    hv.x = gelu_exact(vn * w1v.x + b1v.x);
    hv.y = gelu_exact(vn * w1v.y + b1v.y);
    hv.z = gelu_exact(vn * w1v.z + b1v.z);
    hv.w = gelu_exact(vn * w1v.w + b1v.w);

    // wave handles 16 rows, 8 in flight (independent butterfly trees)
    const int rbase = o * 64 + wave * 16;  // global row within bin
    for (int rg = 0; rg < 16; rg += 8) {
        float p[8];
        #pragma unroll
        for (int k = 0; k < 8; ++k) {
            const int d = rbase + rg + k;
            const float4 w2v = *(const float4*)(vel_w2 + (size_t)d * 256 + lane * 4);
            p[k] = w2v.x * hv.x + w2v.y * hv.y + w2v.z * hv.z + w2v.w * hv.w;
        }
        #pragma unroll
        for (int off = 32; off > 0; off >>= 1) {
            #pragma unroll
            for (int k = 0; k < 8; ++k) p[k] += __shfl_xor(p[k], off);
        }
        #pragma unroll
        for (int k = 0; k < 8; ++k) {
            if (lane == k) e_lds[wave * 16 + rg + k] = p[k] + vel_b2[rbase + rg + k];
        }
    }
    __syncthreads();

    // wave 0: write e to ws + per-octant partial stats
    if (tid < 64) {
        const float e = e_lds[tid];
        e_tab[(size_t)b * DD + o * 64 + tid] = e;
        float s = e, q = e * e;
        #pragma unroll
        for (int off = 32; off > 0; off >>= 1) {
            s += __shfl_xor(s, off);
            q += __shfl_xor(q, off);
        }
        if (tid == 0) {
            stats[((size_t)b * 8 + o) * 2]     = s;
            stats[((size_t)b * 8 + o) * 2 + 1] = q;
        }
    }
}

// ---------------------------------------------------------------------------
// Main: one float4 chunk per thread (no loop). Token wave-uniform.
// Velocity LN applied inline from e_tab + partial stats. Nontemporal stores.
// ---------------------------------------------------------------------------
__global__ __launch_bounds__(256) void direct_kernel(
    const int* __restrict__ tokens,
    const float* __restrict__ token_emb,
    const float* __restrict__ time_lin_w, const float* __restrict__ time_lin_b,
    const float* __restrict__ time_w,     const float* __restrict__ time_b,
    const float* __restrict__ dur_lin_w,  const float* __restrict__ dur_lin_b,
    const float* __restrict__ dur_w,      const float* __restrict__ dur_b,
    const float* __restrict__ vel_ln_g,   const float* __restrict__ vel_ln_b,
    const float* __restrict__ e_tab,      const float* __restrict__ stats,
    float* __restrict__ out, int total_chunks)
{
    const int c = blockIdx.x * 256 + threadIdx.x;
    if (c >= total_chunks) return;

    const int tok = c >> 7;        // token index
    const int ch  = c & 127;       // chunk within row
    const int d   = ch * 4;        // first dim of chunk
    const int t   = tokens[tok];   // wave-uniform (broadcast load)

    f32x4 v;

    if (t < CAT_VOCAB) {
        v = *(const f32x4*)(token_emb + (size_t)t * DD + d);
    } else if (t < NOTE_START || t >= DUR_START) {
        const bool is_time = (t < NOTE_START);
        const int start = is_time ? TIME_START : DUR_START;
        const float tn = (float)(t - start) / 1000.0f;
        if (ch < 64) {   // linear half, dims [0,256)
            const float* lw = is_time ? time_lin_w : dur_lin_w;
            const float* lb = is_time ? time_lin_b : dur_lin_b;
            const float4 w = *(const float4*)(lw + d);
            const float4 b = *(const float4*)(lb + d);
            v.x = tn * w.x + b.x; v.y = tn * w.y + b.y;
            v.z = tn * w.z + b.z; v.w = tn * w.w + b.w;
        } else {         // periodic half, dims [256,512)
            const float* pw = is_time ? time_w : dur_w;
            const float* pb = is_time ? time_b : dur_b;
            const float4 w = *(const float4*)(pw + d - 256);
            const float4 b = *(const float4*)(pb + d - 256);
            v.x = fsin(tn * w.x + b.x); v.y = fsin(tn * w.y + b.y);
            v.z = fsin(tn * w.z + b.z); v.w = fsin(tn * w.w + b.w);
        }
    } else if (t < VEL_START) {
        // pitch: group i = ch, dims (sin po, cos po, sin ps, cos ps)
        const int p = t - NOTE_START;
        const float oct = (float)(p / 12);
        const float sem = (float)(p % 12);
        const float po = oct * __builtin_amdgcn_exp2f(-(float)ch);
        const float ps = sem * 0.52359877559829887308f * ((float)ch + 1.0f);
        v.x = fsin(po); v.y = fcos(po); v.z = fsin(ps); v.w = fcos(ps);
    } else {
        // velocity: raw e from ws + inline LayerNorm from partial stats
        const int bin = t - VEL_START;
        const f32x4 e = *(const f32x4*)(e_tab + (size_t)bin * DD + d);
        float s = 0.0f, q = 0.0f;
        #pragma unroll
        for (int o = 0; o < 8; ++o) {
            s += stats[((size_t)bin * 8 + o) * 2];
            q += stats[((size_t)bin * 8 + o) * 2 + 1];
        }
        const float mu  = s * (1.0f / 512.0f);
        const float var = q * (1.0f / 512.0f) - mu * mu;
        const float inv = 1.0f / sqrtf(var + 1e-5f);
        const float4 g  = *(const float4*)(vel_ln_g + d);
        const float4 be = *(const float4*)(vel_ln_b + d);
        v.x = g.x * (e.x - mu) * inv + be.x;
        v.y = g.y * (e.y - mu) * inv + be.y;
        v.z = g.z * (e.z - mu) * inv + be.z;
        v.w = g.w * (e.w - mu) * inv + be.w;
    }

    __builtin_nontemporal_store(v, (f32x4*)(out + (size_t)c * 4));
}

// ---------------------------------------------------------------------------
// Fallback (ws too small): direct per-token kernel (R1).
// ---------------------------------------------------------------------------
__global__ __launch_bounds__(256) void music_emb_fallback(
    const int* __restrict__ tokens,
    const float* __restrict__ token_emb,
    const float* __restrict__ time_lin_w, const float* __restrict__ time_lin_b,
    const float* __restrict__ time_w,     const float* __restrict__ time_b,
    const float* __restrict__ vel_w1,     const float* __restrict__ vel_b1,
    const float* __restrict__ vel_w2,     const float* __restrict__ vel_b2,
    const float* __restrict__ vel_ln_g,   const float* __restrict__ vel_ln_b,
    const float* __restrict__ dur_lin_w,  const float* __restrict__ dur_lin_b,
    const float* __restrict__ dur_w,      const float* __restrict__ dur_b,
    float* __restrict__ out, int n_tokens)
{
    const int wave = threadIdx.x >> 6;
    const int lane = threadIdx.x & 63;
    const int tok_idx = blockIdx.x * 4 + wave;
    if (tok_idx >= n_tokens) return;

    const int t = tokens[tok_idx];
    float* __restrict__ orow = out + (size_t)tok_idx * DD;
    const int d0 = lane * 4;
    const int d1 = 256 + lane * 4;
    float4 r0, r1;

    if (t < CAT_VOCAB) {
        r0 = *(const float4*)(token_emb + (size_t)t * DD + d0);
        r1 = *(const float4*)(token_emb + (size_t)t * DD + d1);
    } else if (t < NOTE_START || (t >= DUR_START && t < DUR_START + DUR_STEPS)) {
        const bool is_time = (t < NOTE_START);
        const float* lw = is_time ? time_lin_w : dur_lin_w;
        const float* lb = is_time ? time_lin_b : dur_lin_b;
        const float* pw = is_time ? time_w    : dur_w;
        const float* pb = is_time ? time_b    : dur_b;
        const int start = is_time ? TIME_START : DUR_START;
        const float tn = (float)(t - start) / 1000.0f;
        float a[4], p[4];
        #pragma unroll
        for (int k = 0; k < 4; ++k) {
            a[k] = tn * lw[d0 + k] + lb[d0 + k];
            p[k] = sinf(tn * pw[d0 + k] + pb[d0 + k]);
        }
        r0 = make_float4(a[0], a[1], a[2], a[3]);
        r1 = make_float4(p[0], p[1], p[2], p[3]);
    } else if (t < NOTE_START + NOTE_RANGE) {
        const int p = t - NOTE_START;
        const float oct = (float)(p / 12);
        const float sem = (float)(p % 12);
        const float cc = 0.52359877559829887308f;
        {
            const float i = (float)lane;
            const float po = oct * exp2f(-i);
            const float ps = (sem * cc) * (i + 1.0f);
            r0 = make_float4(sinf(po), cosf(po), sinf(ps), cosf(ps));
        }
        {
            const float i = (float)(64 + lane);
            const float po = oct * exp2f(-i);
            const float ps = (sem * cc) * (i + 1.0f);
            r1 = make_float4(sinf(po), cosf(po), sinf(ps), cosf(ps));
        }
    } else if (t < VEL_START + VEL_BINS) {
        const float vn = (float)(t - VEL_START) / 32.0f;
        float hj[4];
        #pragma unroll
        for (int k = 0; k < 4; ++k) {
            const float x = vn * vel_w1[d0 + k] + vel_b1[d0 + k];
            hj[k] = gelu_exact(x);
        }
        float e0[4], e1[4];
        #pragma unroll
        for (int k = 0; k < 4; ++k) { e0[k] = vel_b2[d0 + k]; e1[k] = vel_b2[d1 + k]; }
        for (int src = 0; src < 64; ++src) {
            const float h0 = __shfl(hj[0], src);
            const float h1 = __shfl(hj[1], src);
            const float h2 = __shfl(hj[2], src);
            const float h3 = __shfl(hj[3], src);
            const int j = src << 2;
            #pragma unroll
            for (int k = 0; k < 4; ++k) {
                const float4 wa = *(const float4*)(vel_w2 + (size_t)(d0 + k) * 256 + j);
                const float4 wb = *(const float4*)(vel_w2 + (size_t)(d1 + k) * 256 + j);
                e0[k] += h0 * wa.x + h1 * wa.y + h2 * wa.z + h3 * wa.w;
                e1[k] += h0 * wb.x + h1 * wb.y + h2 * wb.z + h3 * wb.w;
            }
        }
        float s1 = 0.0f;
        #pragma unroll
        for (int k = 0; k < 4; ++k) s1 += e0[k] + e1[k];
        #pragma unroll
        for (int off = 32; off > 0; off >>= 1) s1 += __shfl_xor(s1, off);
        const float mu = s1 * (1.0f / 512.0f);
        float s2 = 0.0f;
        #pragma unroll
        for (int k = 0; k < 4; ++k) {
            const float a = e0[k] - mu, bb = e1[k] - mu;
            s2 += a * a + bb * bb;
        }
        #pragma unroll
        for (int off = 32; off > 0; off >>= 1) s2 += __shfl_xor(s2, off);
        const float inv = 1.0f / sqrtf(s2 * (1.0f / 512.0f) + 1e-5f);
        #pragma unroll
        for (int k = 0; k < 4; ++k) {
            e0[k] = vel_ln_g[d0 + k] * (e0[k] - mu) * inv + vel_ln_b[d0 + k];
            e1[k] = vel_ln_g[d1 + k] * (e1[k] - mu) * inv + vel_ln_b[d1 + k];
        }
        r0 = make_float4(e0[0], e0[1], e0[2], e0[3]);
        r1 = make_float4(e1[0], e1[1], e1[2], e1[3]);
    } else {
        r0 = make_float4(0.f, 0.f, 0.f, 0.f);
        r1 = make_float4(0.f, 0.f, 0.f, 0.f);
    }

    *(float4*)(orow + d0) = r0;
    *(float4*)(orow + d1) = r1;
}

extern "C" void kernel_launch(void* const* d_in, const int* in_sizes, int n_in,
                              void* d_out, int out_size, void* d_ws, size_t ws_size,
                              hipStream_t stream) {
    const int*   tokens     = (const int*)  d_in[0];
    const float* token_emb  = (const float*)d_in[1];
    const float* time_lin_w = (const float*)d_in[2];
    const float* time_lin_b = (const float*)d_in[3];
    const float* time_w     = (const float*)d_in[4];
    const float* time_b     = (const float*)d_in[5];
    const float* vel_w1     = (const float*)d_in[6];
    const float* vel_b1     = (const float*)d_in[7];
    const float* vel_w2     = (const float*)d_in[8];
    const float* vel_b2     = (const float*)d_in[9];
    const float* vel_ln_g   = (const float*)d_in[10];
    const float* vel_ln_b   = (const float*)d_in[11];
    const float* dur_lin_w  = (const float*)d_in[12];
    const float* dur_lin_b  = (const float*)d_in[13];
    const float* dur_w      = (const float*)d_in[14];
    const float* dur_b      = (const float*)d_in[15];
    float* out = (float*)d_out;

    const int n_tokens = in_sizes[0];                                    // 65536
    const size_t e_bytes     = (size_t)VEL_BINS * DD * sizeof(float);    // 64 KB
    const size_t stats_bytes = (size_t)VEL_BINS * 8 * 2 * sizeof(float); // 2 KB

    if (ws_size >= e_bytes + stats_bytes) {
        float* e_tab = (float*)d_ws;
        float* stats = (float*)((char*)d_ws + e_bytes);

        hipLaunchKernelGGL(vel_e_kernel, dim3(VEL_BINS * 8), dim3(256), 0, stream,
                           vel_w1, vel_b1, vel_w2, vel_b2, e_tab, stats);

        const int total_chunks = n_tokens * (DD / 4);                    // 8,388,608
        const int blocks = (total_chunks + 255) / 256;                   // 32768
        hipLaunchKernelGGL(direct_kernel, dim3(blocks), dim3(256), 0, stream,
                           tokens, token_emb,
                           time_lin_w, time_lin_b, time_w, time_b,
                           dur_lin_w, dur_lin_b, dur_w, dur_b,
                           vel_ln_g, vel_ln_b, e_tab, stats,
                           out, total_chunks);
    } else {
        const int blocks = (n_tokens + 3) / 4;
        hipLaunchKernelGGL(music_emb_fallback, dim3(blocks), dim3(256), 0, stream,
                           tokens, token_emb,
                           time_lin_w, time_lin_b, time_w, time_b,
                           vel_w1, vel_b1, vel_w2, vel_b2, vel_ln_g, vel_ln_b,
                           dur_lin_w, dur_lin_b, dur_w, dur_b,
                           out, n_tokens);
    }
}